// Round 4
// baseline (66455.200 us; speedup 1.0000x reference)
//
#include <hip/hip_runtime.h>

typedef __attribute__((ext_vector_type(8))) short short8;
typedef __attribute__((ext_vector_type(4))) float f32x4;
typedef __attribute__((ext_vector_type(4))) int i32x4;

#define NBLK 256
#define NTHR 512
#define BSZ 128
#define HID 1024
#define INP 256
#define LAT 512
#define OUTD 256

// ---- bf16 element offsets in ws ----
#define E_ZB   0u
#define E_XB   65536u
#define E_HZ   98304u
#define E_CZB  229376u
#define E_H0N  360448u
#define E_H1N  491520u
#define E_H0F  622592u
#define E_H1F  753664u
#define E_C0NB 884736u
#define E_C1NB 1015808u
#define E_RB   1146880u
#define E_END  1277952u
#define F32BASE (2u*E_END)
#define OF_GHZ 0u
#define OF_GCZ 131072u
#define OF_CZ  262144u
#define OF_C0N 393216u
#define OF_C1N 524288u
#define OF_C0F 655360u
#define OF_C1F 786432u
#define F32CNT 917504u
#define BARBYTE (F32BASE + 4u*F32CNT)

__device__ __forceinline__ unsigned short f2bf(float x) {
  union { float f; unsigned u; } v; v.f = x;
  return (unsigned short)((v.u + 0x7fffu + ((v.u >> 16) & 1u)) >> 16);
}
__device__ __forceinline__ float bf2f(unsigned short h) {
  union { unsigned u; float f; } v; v.u = ((unsigned)h) << 16;
  return v.f;
}
__device__ __forceinline__ float sigm(float x) { return 1.f / (1.f + __expf(-x)); }
__device__ __forceinline__ float ftanh(float x) { return 1.f - 2.f / (__expf(2.f * x) + 1.f); }

// opaque SSA identity: value flows THROUGH the volatile asm, so later uses
// depend on the asm result — loads feeding it cannot be rematerialized.
__device__ __forceinline__ void pinw(short8& v) {
  i32x4 t = __builtin_bit_cast(i32x4, v);
  asm volatile("" : "+v"(t));
  v = __builtin_bit_cast(short8, t);
}
__device__ __forceinline__ void pinf(float& v) {
  asm volatile("" : "+v"(v));
}

__device__ __forceinline__ short8 ldwf(const float* s) {
  const float4* p = (const float4*)s;
  float4 x = p[0], y = p[1];
  short8 r;
  r[0]=(short)f2bf(x.x); r[1]=(short)f2bf(x.y); r[2]=(short)f2bf(x.z); r[3]=(short)f2bf(x.w);
  r[4]=(short)f2bf(y.x); r[5]=(short)f2bf(y.y); r[6]=(short)f2bf(y.z); r[7]=(short)f2bf(y.w);
  return r;
}

__device__ __forceinline__ void conv4(const float* __restrict__ s,
                                      unsigned short* __restrict__ d,
                                      int n4, int gtid, int gsz) {
  const float4* s4 = (const float4*)s;
  ushort4* d4 = (ushort4*)d;
  for (int i = gtid; i < n4; i += gsz) {
    float4 v = s4[i];
    ushort4 o;
    o.x = f2bf(v.x); o.y = f2bf(v.y); o.z = f2bf(v.z); o.w = f2bf(v.w);
    d4[i] = o;
  }
}

// two-level grid barrier
__device__ __forceinline__ void gbar(unsigned* bar, unsigned target) {
  __syncthreads();
  if (threadIdx.x == 0) {
    unsigned* cnt  = bar + ((int)blockIdx.x & 7) * 32;
    unsigned* root = bar + 8 * 32;
    unsigned* ep   = bar + 9 * 32;
    unsigned prev = __hip_atomic_fetch_add(cnt, 1u, __ATOMIC_ACQ_REL, __HIP_MEMORY_SCOPE_AGENT);
    if (prev == 31u) {
      __hip_atomic_store(cnt, 0u, __ATOMIC_RELAXED, __HIP_MEMORY_SCOPE_AGENT);
      unsigned p2 = __hip_atomic_fetch_add(root, 1u, __ATOMIC_ACQ_REL, __HIP_MEMORY_SCOPE_AGENT);
      if (p2 == 7u) {
        __hip_atomic_store(root, 0u, __ATOMIC_RELAXED, __HIP_MEMORY_SCOPE_AGENT);
        __hip_atomic_store(ep, target, __ATOMIC_RELEASE, __HIP_MEMORY_SCOPE_AGENT);
      }
    }
    unsigned e = __hip_atomic_load(ep, __ATOMIC_RELAXED, __HIP_MEMORY_SCOPE_AGENT);
    int guard = 0;
    while (e < target) {
      __builtin_amdgcn_s_sleep(2);
      e = __hip_atomic_load(ep, __ATOMIC_RELAXED, __HIP_MEMORY_SCOPE_AGENT);
      if (++guard > (1 << 21)) break;
    }
    __builtin_amdgcn_fence(__ATOMIC_ACQUIRE, "agent");
  }
  __syncthreads();
}

template<int NF>
__device__ __forceinline__ void mm_reg(const unsigned short* __restrict__ a0, int p0, int len0,
                                       const unsigned short* __restrict__ a1, int p1,
                                       const short8* w, int kbeg, int lm, int lq8,
                                       f32x4* acc) {
#pragma unroll
  for (int i = 0; i < NF; ++i) {
    int vk = kbeg + i * 32;
    const unsigned short* ab; int pa, kk;
    if (vk < len0) { ab = a0; pa = p0; kk = vk; } else { ab = a1; pa = p1; kk = vk - len0; }
    const unsigned short* base = ab + (size_t)lm * pa + kk + lq8;
#pragma unroll
    for (int m = 0; m < 8; ++m) {
      short8 afr = *(const short8*)(base + (size_t)(m * 16) * pa);
      acc[m] = __builtin_amdgcn_mfma_f32_16x16x32_bf16(afr, w[i], acc[m], 0, 0, 0);
    }
  }
}

template<int NF>
__device__ __forceinline__ void mm_f32w(const unsigned short* __restrict__ a, int pa,
                                        const float* __restrict__ w, int pw, int col,
                                        int kbeg, int lm, int lq8, f32x4* acc) {
#pragma unroll
  for (int i = 0; i < NF; ++i) {
    int kk = kbeg + i * 32;
    short8 bfr = ldwf(w + (size_t)col * pw + kk + lq8);
    const unsigned short* base = a + (size_t)lm * pa + kk + lq8;
#pragma unroll
    for (int m = 0; m < 8; ++m) {
      short8 afr = *(const short8*)(base + (size_t)(m * 16) * pa);
      acc[m] = __builtin_amdgcn_mfma_f32_16x16x32_bf16(afr, bfr, acc[m], 0, 0, 0);
    }
  }
}

__device__ __forceinline__ void dump(float* lds, f32x4* acc, int wave, int lane) {
  int lm = lane & 15, lq = lane >> 4;
#pragma unroll
  for (int m = 0; m < 8; ++m)
#pragma unroll
    for (int j = 0; j < 4; ++j)
      lds[(wave * 128 + m * 16 + lq * 4 + j) * 16 + lm] = acc[m][j];
}

__device__ __forceinline__ float red8(const float* lds, int r, int c) {
  float s = 0.f;
#pragma unroll
  for (int w = 0; w < 8; ++w) s += lds[(w * 128 + r) * 16 + c];
  return s;
}

__global__ __launch_bounds__(NTHR, 1)
void dec_kernel(const float* __restrict__ z, const int* __restrict__ seqp,
                const float* __restrict__ stok,
                const float* __restrict__ W_ih0, const float* __restrict__ W_hh0,
                const float* __restrict__ b_ih0, const float* __restrict__ b_hh0,
                const float* __restrict__ W_ih1, const float* __restrict__ W_hh1,
                const float* __restrict__ b_ih1, const float* __restrict__ b_hh1,
                const float* __restrict__ W_lh, const float* __restrict__ b_lh,
                const float* __restrict__ W_lc, const float* __restrict__ b_lc,
                const float* __restrict__ W_fc1, const float* __restrict__ b_fc1,
                const float* __restrict__ W_fc2, const float* __restrict__ b_fc2,
                const float* __restrict__ Wg_h, const float* __restrict__ bg_h,
                const float* __restrict__ Wg_c, const float* __restrict__ bg_c,
                float* __restrict__ out, unsigned char* __restrict__ ws) {
  __shared__ float lds[8 * 128 * 16];

  unsigned short* bfb = (unsigned short*)ws;
  float* f32b = (float*)(ws + F32BASE);
  unsigned* bar = (unsigned*)(ws + BARBYTE);

  unsigned short* Zb  = bfb + E_ZB;
  unsigned short* Xb  = bfb + E_XB;
  unsigned short* Hz  = bfb + E_HZ;
  unsigned short* Czb = bfb + E_CZB;
  unsigned short* H0n = bfb + E_H0N;
  unsigned short* H1n = bfb + E_H1N;
  unsigned short* H0f = bfb + E_H0F;
  unsigned short* H1f = bfb + E_H1F;
  unsigned short* C0nb = bfb + E_C0NB;
  unsigned short* C1nb = bfb + E_C1NB;
  unsigned short* Rb  = bfb + E_RB;
  float* Ghz = f32b + OF_GHZ;
  float* Gcz = f32b + OF_GCZ;
  float* Cz  = f32b + OF_CZ;
  float* C0n = f32b + OF_C0N;
  float* C1n = f32b + OF_C1N;
  float* C0f = f32b + OF_C0F;
  float* C1f = f32b + OF_C1F;

  const int b = (int)blockIdx.x, tid = (int)threadIdx.x;
  const int lane = tid & 63, wave = tid >> 6;
  const int lm = lane & 15, lq8 = (lane >> 4) * 8;
  const int gtid = b * NTHR + tid, gsz = NBLK * NTHR;
  const int c3 = tid & 15;
  const int n03 = 16 * (b & 63);
  unsigned bt = 0;

  // ---- Ph_a ----
  conv4(z, Zb, (BSZ * LAT) / 4, gtid, gsz);
  for (int i = gtid; i < BSZ * INP; i += gsz) Xb[i] = f2bf(stok[i & (INP - 1)]);
  gbar(bar, ++bt);

  // ---- Ph_b: h_z / c_z ----
  {
    if (b < 128) {
      f32x4 acc[8] = {};
      const float* Wm = (b < 64) ? W_lh : W_lc;
      mm_f32w<2>(Zb, LAT, Wm, LAT, n03 + lm, wave * 64, lm, lq8, acc);
      dump(lds, acc, wave, lane);
    }
    __syncthreads();
    if (b < 64) {
#pragma unroll
      for (int q = 0; q < 4; ++q) {
        int rq = q * 32 + (tid >> 4);
        float v = ftanh(red8(lds, rq, c3) + b_lh[n03 + c3]);
        unsigned short bv = f2bf(v);
        int i = rq * HID + n03 + c3;
        Hz[i] = bv; H0f[i] = bv; H1f[i] = bv;
      }
    } else if (b < 128) {
#pragma unroll
      for (int q = 0; q < 4; ++q) {
        int rq = q * 32 + (tid >> 4);
        float v = ftanh(red8(lds, rq, c3) + b_lc[n03 + c3]);
        int i = rq * HID + n03 + c3;
        Czb[i] = f2bf(v); Cz[i] = v; C0f[i] = v; C1f[i] = v;
      }
    }
    gbar(bar, ++bt);
  }

  // ---- Ph_c: Ghz / Gcz ----
  {
    if (b < 128) {
      f32x4 acc[8] = {};
      const unsigned short* A = (b < 64) ? Hz : Czb;
      const float* Wm = ((b < 64) ? Wg_h : Wg_c) + HID;
      mm_f32w<4>(A, HID, Wm, 2 * HID, n03 + lm, wave * 128, lm, lq8, acc);
      dump(lds, acc, wave, lane);
    }
    __syncthreads();
    if (b < 64) {
#pragma unroll
      for (int q = 0; q < 4; ++q) {
        int rq = q * 32 + (tid >> 4);
        Ghz[rq * HID + n03 + c3] = red8(lds, rq, c3) + bg_h[n03 + c3];
      }
    } else if (b < 128) {
#pragma unroll
      for (int q = 0; q < 4; ++q) {
        int rq = q * 32 + (tid >> 4);
        Gcz[rq * HID + n03 + c3] = red8(lds, rq, c3) + bg_c[n03 + c3];
      }
    }
    gbar(bar, ++bt);
  }

  // ---- preload step-invariant scalars (pinned) ----
  const int du_ = tid & 3, rrow = tid >> 2;
  const int uu = 4 * b + du_;
  float bi0 = b_ih0[uu] + b_hh0[uu];
  float bf0 = b_ih0[HID + uu] + b_hh0[HID + uu];
  float bg0 = b_ih0[2 * HID + uu] + b_hh0[2 * HID + uu];
  float bo0 = b_ih0[3 * HID + uu] + b_hh0[3 * HID + uu];
  float bi1 = b_ih1[uu] + b_hh1[uu];
  float bf1 = b_ih1[HID + uu] + b_hh1[HID + uu];
  float bg1 = b_ih1[2 * HID + uu] + b_hh1[2 * HID + uu];
  float bo1 = b_ih1[3 * HID + uu] + b_hh1[3 * HID + uu];
  pinf(bi0); pinf(bf0); pinf(bg0); pinf(bo0);
  pinf(bi1); pinf(bf1); pinf(bg1); pinf(bo1);

  float p3b = 0.f, p3g[4] = {}, p3z[4] = {};
  if (b < 64) p3b = b_fc1[n03 + c3];
  else if (b < 128) {
#pragma unroll
    for (int q = 0; q < 4; ++q) { int i = (q * 32 + (tid >> 4)) * HID + n03 + c3; p3g[q] = Ghz[i]; p3z[q] = bf2f(Hz[i]); }
  } else if (b < 192) {
#pragma unroll
    for (int q = 0; q < 4; ++q) { int i = (q * 32 + (tid >> 4)) * HID + n03 + c3; p3g[q] = Gcz[i]; p3z[q] = Cz[i]; }
  }
  pinf(p3b);
#pragma unroll
  for (int q = 0; q < 4; ++q) { pinf(p3g[q]); pinf(p3z[q]); }

  const int n04 = (b < 16) ? 16 * b : (b < 80) ? 16 * (b - 16) : 16 * (b - 80);
  float p4b = 0.f, p4g[4] = {}, p4z[4] = {};
  if (b < 16) p4b = b_fc2[n04 + c3];
  else if (b < 80) {
#pragma unroll
    for (int q = 0; q < 4; ++q) { int i = (q * 32 + (tid >> 4)) * HID + n04 + c3; p4g[q] = Ghz[i]; p4z[q] = bf2f(Hz[i]); }
  } else if (b < 144) {
#pragma unroll
    for (int q = 0; q < 4; ++q) { int i = (q * 32 + (tid >> 4)) * HID + n04 + c3; p4g[q] = Gcz[i]; p4z[q] = Cz[i]; }
  }
  pinf(p4b);
#pragma unroll
  for (int q = 0; q < 4; ++q) { pinf(p4g[q]); pinf(p4z[q]); }

  // ---- load persistent weight B-fragments into registers (pinned) ----
  const int gcol = (lm >> 2) * HID + 4 * b + (lm & 3);
  short8 wP1[5], wP2[8], wP3[4], wP4[4];
#pragma unroll
  for (int i = 0; i < 5; ++i) {
    int vk = wave * 160 + i * 32;
    wP1[i] = (vk < INP) ? ldwf(W_ih0 + (size_t)gcol * INP + vk + lq8)
                        : ldwf(W_hh0 + (size_t)gcol * HID + (vk - INP) + lq8);
    pinw(wP1[i]);
  }
#pragma unroll
  for (int i = 0; i < 8; ++i) {
    int vk = wave * 256 + i * 32;
    wP2[i] = (vk < HID) ? ldwf(W_ih1 + (size_t)gcol * HID + vk + lq8)
                        : ldwf(W_hh1 + (size_t)gcol * HID + (vk - HID) + lq8);
    pinw(wP2[i]);
  }
  if (b < 192) {
    const float* Wp; size_t pw;
    if (b < 64)       { Wp = W_fc1; pw = HID; }
    else if (b < 128) { Wp = Wg_h;  pw = 2 * HID; }
    else              { Wp = Wg_c;  pw = 2 * HID; }
#pragma unroll
    for (int i = 0; i < 4; ++i) {
      wP3[i] = ldwf(Wp + (size_t)(n03 + lm) * pw + wave * 128 + i * 32 + lq8);
    }
  }
#pragma unroll
  for (int i = 0; i < 4; ++i) pinw(wP3[i]);
  if (b < 144) {
    const float* Wp; size_t pw;
    if (b < 16)      { Wp = W_fc2; pw = HID; }
    else if (b < 80) { Wp = Wg_h;  pw = 2 * HID; }
    else             { Wp = Wg_c;  pw = 2 * HID; }
#pragma unroll
    for (int i = 0; i < 4; ++i) {
      wP4[i] = ldwf(Wp + (size_t)(n04 + lm) * pw + wave * 128 + i * 32 + lq8);
    }
  }
#pragma unroll
  for (int i = 0; i < 4; ++i) pinw(wP4[i]);

  const int T = seqp[0];

  for (int t = 0; t < T; ++t) {
    // ---- P1 ----
    {
      f32x4 acc[8] = {};
      mm_reg<5>(Xb, INP, INP, H0f, HID, wP1, wave * 160, lm, lq8, acc);
      dump(lds, acc, wave, lane);
      __syncthreads();
      {
        float s0 = red8(lds, rrow, du_), s1 = red8(lds, rrow, 4 + du_);
        float s2 = red8(lds, rrow, 8 + du_), s3 = red8(lds, rrow, 12 + du_);
        float gi = sigm(s0 + bi0), gf = sigm(s1 + bf0), gg = ftanh(s2 + bg0), go = sigm(s3 + bo0);
        int i = rrow * HID + uu;
        float cn = gf * C0f[i] + gi * gg;
        H0n[i] = f2bf(go * ftanh(cn));
        C0n[i] = cn; C0nb[i] = f2bf(cn);
      }
      gbar(bar, ++bt);
    }
    // ---- P2 ----
    {
      f32x4 acc[8] = {};
      mm_reg<8>(H0n, HID, HID, H1f, HID, wP2, wave * 256, lm, lq8, acc);
      dump(lds, acc, wave, lane);
      __syncthreads();
      {
        float s0 = red8(lds, rrow, du_), s1 = red8(lds, rrow, 4 + du_);
        float s2 = red8(lds, rrow, 8 + du_), s3 = red8(lds, rrow, 12 + du_);
        float gi = sigm(s0 + bi1), gf = sigm(s1 + bf1), gg = ftanh(s2 + bg1), go = sigm(s3 + bo1);
        int i = rrow * HID + uu;
        float cn = gf * C1f[i] + gi * gg;
        H1n[i] = f2bf(go * ftanh(cn));
        C1n[i] = cn; C1nb[i] = f2bf(cn);
      }
      gbar(bar, ++bt);
    }
    // ---- P3 ----
    {
      if (b < 192) {
        f32x4 acc[8] = {};
        const unsigned short* A = (b < 64) ? H1n : (b < 128) ? H0n : C0nb;
        mm_reg<4>(A, HID, 1 << 30, A, HID, wP3, wave * 128, lm, lq8, acc);
        dump(lds, acc, wave, lane);
      }
      __syncthreads();
      if (b < 64) {
#pragma unroll
        for (int q = 0; q < 4; ++q) {
          int rq = q * 32 + (tid >> 4);
          float v = red8(lds, rq, c3) + p3b;
          Rb[rq * HID + n03 + c3] = f2bf(v > 0.f ? v : 0.f);
        }
      } else if (b < 128) {
#pragma unroll
        for (int q = 0; q < 4; ++q) {
          int rq = q * 32 + (tid >> 4); int i = rq * HID + n03 + c3;
          float g = sigm(red8(lds, rq, c3) + p3g[q]);
          H0f[i] = f2bf(g * bf2f(H0n[i]) + (1.f - g) * p3z[q]);
        }
      } else if (b < 192) {
#pragma unroll
        for (int q = 0; q < 4; ++q) {
          int rq = q * 32 + (tid >> 4); int i = rq * HID + n03 + c3;
          float g = sigm(red8(lds, rq, c3) + p3g[q]);
          C0f[i] = g * C0n[i] + (1.f - g) * p3z[q];
        }
      }
      gbar(bar, ++bt);
    }
    // ---- P4 ----
    {
      if (b < 144) {
        f32x4 acc[8] = {};
        const unsigned short* A = (b < 16) ? Rb : (b < 80) ? H1n : C1nb;
        mm_reg<4>(A, HID, 1 << 30, A, HID, wP4, wave * 128, lm, lq8, acc);
        dump(lds, acc, wave, lane);
      }
      __syncthreads();
      if (b < 16) {
#pragma unroll
        for (int q = 0; q < 4; ++q) {
          int rq = q * 32 + (tid >> 4);
          float v = red8(lds, rq, c3) + p4b;
          out[((long)rq * T + t) * OUTD + n04 + c3] = v;
          Xb[rq * INP + n04 + c3] = f2bf(v);
        }
      } else if (b < 80) {
#pragma unroll
        for (int q = 0; q < 4; ++q) {
          int rq = q * 32 + (tid >> 4); int i = rq * HID + n04 + c3;
          float g = sigm(red8(lds, rq, c3) + p4g[q]);
          H1f[i] = f2bf(g * bf2f(H1n[i]) + (1.f - g) * p4z[q]);
        }
      } else if (b < 144) {
#pragma unroll
        for (int q = 0; q < 4; ++q) {
          int rq = q * 32 + (tid >> 4); int i = rq * HID + n04 + c3;
          float g = sigm(red8(lds, rq, c3) + p4g[q]);
          C1f[i] = g * C1n[i] + (1.f - g) * p4z[q];
        }
      }
      gbar(bar, ++bt);
    }
  }
}

extern "C" void kernel_launch(void* const* d_in, const int* in_sizes, int n_in,
                              void* d_out, int out_size, void* d_ws, size_t ws_size,
                              hipStream_t stream) {
  unsigned char* ws = (unsigned char*)d_ws;
  hipMemsetAsync(ws + BARBYTE, 0, 2048, stream);

  dec_kernel<<<dim3(NBLK), dim3(NTHR), 0, stream>>>(
      (const float*)d_in[0], (const int*)d_in[1], (const float*)d_in[2],
      (const float*)d_in[3], (const float*)d_in[4], (const float*)d_in[5], (const float*)d_in[6],
      (const float*)d_in[7], (const float*)d_in[8], (const float*)d_in[9], (const float*)d_in[10],
      (const float*)d_in[11], (const float*)d_in[12], (const float*)d_in[13], (const float*)d_in[14],
      (const float*)d_in[15], (const float*)d_in[16], (const float*)d_in[17], (const float*)d_in[18],
      (const float*)d_in[19], (const float*)d_in[20], (const float*)d_in[21], (const float*)d_in[22],
      (float*)d_out, ws);
}

// Round 5
// 59151.770 us; speedup vs baseline: 1.1235x; 1.1235x over previous
//
#include <hip/hip_runtime.h>

typedef __attribute__((ext_vector_type(8))) short short8;
typedef __attribute__((ext_vector_type(4))) float f32x4;

#define NBLK 256
#define NTHR 512
#define BSZ 128
#define HID 1024
#define INP 256
#define LAT 512
#define OUTD 256

// ---- workspace layout (bf16 element offsets) ----
#define O_WIH0 0u
#define O_WHH0 1048576u
#define O_WIH1 5242880u
#define O_WHH1 9437184u
#define O_WFC1 13631488u
#define O_WFC2 14680064u
#define O_WGH  14942208u
#define O_WGC  17039360u
#define O_ZBF  19136512u
#define O_XBUF 19202048u
#define O_HZ   19234816u
#define O_CZB  19365888u
#define O_H0N  19496960u
#define O_H1N  19628032u
#define O_H0F  19759104u
#define O_H1F  19890176u
#define O_C0NB 20021248u
#define O_C1NB 20152320u
#define O_RBUF 20283392u
#define BF_END 20414464u
#define F32BASE (2u*BF_END)
#define OF_GHZ 0u
#define OF_GCZ 131072u
#define OF_CZ  262144u
#define OF_C0N 393216u
#define OF_C1N 524288u
#define OF_C0F 655360u
#define OF_C1F 786432u
#define F32CNT 917504u
#define BARBYTE (F32BASE + 4u*F32CNT)

__device__ __forceinline__ unsigned short f2bf(float x) {
  union { float f; unsigned u; } v; v.f = x;
  return (unsigned short)((v.u + 0x7fffu + ((v.u >> 16) & 1u)) >> 16);
}
__device__ __forceinline__ float bf2f(unsigned short h) {
  union { unsigned u; float f; } v; v.u = ((unsigned)h) << 16;
  return v.f;
}
__device__ __forceinline__ float sigm(float x) { return 1.f / (1.f + __expf(-x)); }
__device__ __forceinline__ float ftanh(float x) { return 1.f - 2.f / (__expf(2.f * x) + 1.f); }

// ---- coherent (agent-scope, L2-bypassing) accessors for cross-block data ----
__device__ __forceinline__ unsigned long long ald64(const void* p) {
  return __hip_atomic_load((const unsigned long long*)p, __ATOMIC_RELAXED, __HIP_MEMORY_SCOPE_AGENT);
}
__device__ __forceinline__ unsigned ald32(const void* p) {
  return __hip_atomic_load((const unsigned*)p, __ATOMIC_RELAXED, __HIP_MEMORY_SCOPE_AGENT);
}
__device__ __forceinline__ float aldf(const float* p) {
  return __hip_atomic_load(p, __ATOMIC_RELAXED, __HIP_MEMORY_SCOPE_AGENT);
}
__device__ __forceinline__ void ast32(void* p, unsigned v) {
  __hip_atomic_store((unsigned*)p, v, __ATOMIC_RELAXED, __HIP_MEMORY_SCOPE_AGENT);
}
__device__ __forceinline__ void astf(float* p, float v) {
  __hip_atomic_store(p, v, __ATOMIC_RELAXED, __HIP_MEMORY_SCOPE_AGENT);
}
__device__ __forceinline__ short8 ald16B(const unsigned short* p) {
  ulonglong2 t;
  t.x = ald64(p);
  t.y = ald64(p + 4);
  return __builtin_bit_cast(short8, t);
}

__device__ __forceinline__ void conv4(const float* __restrict__ s,
                                      unsigned short* __restrict__ d,
                                      int n4, int gtid, int gsz) {
  const float4* s4 = (const float4*)s;
  ushort4* d4 = (ushort4*)d;
  for (int i = gtid; i < n4; i += gsz) {
    float4 v = s4[i];
    ushort4 o;
    o.x = f2bf(v.x); o.y = f2bf(v.y); o.z = f2bf(v.z); o.w = f2bf(v.w);
    d4[i] = o;
  }
}

// full-fence barrier (prologue only; invalidates L2 — acceptable 3x at startup)
__device__ __forceinline__ void gbar_f(unsigned* bar, unsigned target) {
  __syncthreads();
  if (threadIdx.x == 0) {
    unsigned* cnt  = bar + ((int)blockIdx.x & 7) * 32;
    unsigned* root = bar + 8 * 32;
    unsigned* ep   = bar + 9 * 32;
    unsigned prev = __hip_atomic_fetch_add(cnt, 1u, __ATOMIC_ACQ_REL, __HIP_MEMORY_SCOPE_AGENT);
    if (prev == 31u) {
      __hip_atomic_store(cnt, 0u, __ATOMIC_RELAXED, __HIP_MEMORY_SCOPE_AGENT);
      unsigned p2 = __hip_atomic_fetch_add(root, 1u, __ATOMIC_ACQ_REL, __HIP_MEMORY_SCOPE_AGENT);
      if (p2 == 7u) {
        __hip_atomic_store(root, 0u, __ATOMIC_RELAXED, __HIP_MEMORY_SCOPE_AGENT);
        __hip_atomic_store(ep, target, __ATOMIC_RELEASE, __HIP_MEMORY_SCOPE_AGENT);
      }
    }
    unsigned e = __hip_atomic_load(ep, __ATOMIC_RELAXED, __HIP_MEMORY_SCOPE_AGENT);
    int guard = 0;
    while (e < target) {
      __builtin_amdgcn_s_sleep(1);
      e = __hip_atomic_load(ep, __ATOMIC_RELAXED, __HIP_MEMORY_SCOPE_AGENT);
      if (++guard > (1 << 22)) break;
    }
    __builtin_amdgcn_fence(__ATOMIC_ACQUIRE, "agent");
  }
  __syncthreads();
}

// fence-free barrier (main loop): release RMWs + relaxed spin, NO acquire fence,
// so the XCD L2s keep weight lines warm. Payload coherence comes from the
// sc0/sc1 atomic accesses on all cross-block activation data.
__device__ __forceinline__ void gbar_nf(unsigned* bar, unsigned target) {
  __syncthreads();   // drains each wave's vmcnt -> payload stores globally visible
  if (threadIdx.x == 0) {
    unsigned* cnt  = bar + ((int)blockIdx.x & 7) * 32;
    unsigned* root = bar + 8 * 32;
    unsigned* ep   = bar + 9 * 32;
    unsigned prev = __hip_atomic_fetch_add(cnt, 1u, __ATOMIC_RELEASE, __HIP_MEMORY_SCOPE_AGENT);
    if (prev == 31u) {
      __hip_atomic_store(cnt, 0u, __ATOMIC_RELAXED, __HIP_MEMORY_SCOPE_AGENT);
      unsigned p2 = __hip_atomic_fetch_add(root, 1u, __ATOMIC_RELEASE, __HIP_MEMORY_SCOPE_AGENT);
      if (p2 == 7u) {
        __hip_atomic_store(root, 0u, __ATOMIC_RELAXED, __HIP_MEMORY_SCOPE_AGENT);
        __hip_atomic_store(ep, target, __ATOMIC_RELEASE, __HIP_MEMORY_SCOPE_AGENT);
      }
    }
    unsigned e = __hip_atomic_load(ep, __ATOMIC_RELAXED, __HIP_MEMORY_SCOPE_AGENT);
    int guard = 0;
    while (e < target) {
      __builtin_amdgcn_s_sleep(1);
      e = __hip_atomic_load(ep, __ATOMIC_RELAXED, __HIP_MEMORY_SCOPE_AGENT);
      if (++guard > (1 << 22)) break;
    }
  }
  __syncthreads();
}

// matmul: A via coherent atomic loads, W via plain (L2-cached) loads from ws
__device__ __forceinline__ void mm8(const unsigned short* a0, int ap0,
                                    const unsigned short* w0, int wp0, int len0,
                                    const unsigned short* a1, int ap1,
                                    const unsigned short* w1, int wp1,
                                    int wcol, int kbeg, int kend, int lane, f32x4* acc) {
  const int lm = lane & 15, lq8 = (lane >> 4) * 8;
  for (int vk = kbeg; vk < kend; vk += 32) {
    const unsigned short *ab, *wb; int pa, pw, kk;
    if (vk < len0) { ab = a0; pa = ap0; wb = w0; pw = wp0; kk = vk; }
    else           { ab = a1; pa = ap1; wb = w1; pw = wp1; kk = vk - len0; }
    short8 bfr = *(const short8*)(wb + (size_t)wcol * pw + kk + lq8);
#pragma unroll
    for (int m = 0; m < 8; ++m) {
      short8 afr = ald16B(ab + (size_t)(m * 16 + lm) * pa + kk + lq8);
      acc[m] = __builtin_amdgcn_mfma_f32_16x16x32_bf16(afr, bfr, acc[m], 0, 0, 0);
    }
  }
}

// prologue matmul: A plain, W f32 converted on the fly
template<int NF>
__device__ __forceinline__ void mm_f32w(const unsigned short* __restrict__ a, int pa,
                                        const float* __restrict__ w, int pw, int col,
                                        int kbeg, int lm, int lq8, f32x4* acc) {
#pragma unroll
  for (int i = 0; i < NF; ++i) {
    int kk = kbeg + i * 32;
    const float4* p = (const float4*)(w + (size_t)col * pw + kk + lq8);
    float4 x = p[0], y = p[1];
    short8 bfr;
    bfr[0]=(short)f2bf(x.x); bfr[1]=(short)f2bf(x.y); bfr[2]=(short)f2bf(x.z); bfr[3]=(short)f2bf(x.w);
    bfr[4]=(short)f2bf(y.x); bfr[5]=(short)f2bf(y.y); bfr[6]=(short)f2bf(y.z); bfr[7]=(short)f2bf(y.w);
    const unsigned short* base = a + (size_t)lm * pa + kk + lq8;
#pragma unroll
    for (int m = 0; m < 8; ++m) {
      short8 afr = *(const short8*)(base + (size_t)(m * 16) * pa);
      acc[m] = __builtin_amdgcn_mfma_f32_16x16x32_bf16(afr, bfr, acc[m], 0, 0, 0);
    }
  }
}

__device__ __forceinline__ void dump(float* lds, f32x4* acc, int wave, int lane) {
  int lm = lane & 15, lq = lane >> 4;
#pragma unroll
  for (int m = 0; m < 8; ++m)
#pragma unroll
    for (int j = 0; j < 4; ++j)
      lds[(wave * 128 + m * 16 + lq * 4 + j) * 16 + lm] = acc[m][j];
}

__device__ __forceinline__ float red8(const float* lds, int r, int c) {
  float s = 0.f;
#pragma unroll
  for (int w = 0; w < 8; ++w) s += lds[(w * 128 + r) * 16 + c];
  return s;
}

__global__ __launch_bounds__(NTHR, 1)
void dec_kernel(const float* __restrict__ z, const int* __restrict__ seqp,
                const float* __restrict__ stok,
                const float* __restrict__ W_ih0, const float* __restrict__ W_hh0,
                const float* __restrict__ b_ih0, const float* __restrict__ b_hh0,
                const float* __restrict__ W_ih1, const float* __restrict__ W_hh1,
                const float* __restrict__ b_ih1, const float* __restrict__ b_hh1,
                const float* __restrict__ W_lh, const float* __restrict__ b_lh,
                const float* __restrict__ W_lc, const float* __restrict__ b_lc,
                const float* __restrict__ W_fc1, const float* __restrict__ b_fc1,
                const float* __restrict__ W_fc2, const float* __restrict__ b_fc2,
                const float* __restrict__ Wg_h, const float* __restrict__ bg_h,
                const float* __restrict__ Wg_c, const float* __restrict__ bg_c,
                float* __restrict__ out, unsigned char* __restrict__ ws) {
  __shared__ float lds[8 * 128 * 16];

  unsigned short* bfb = (unsigned short*)ws;
  float* f32b = (float*)(ws + F32BASE);
  unsigned* bar = (unsigned*)(ws + BARBYTE);

  unsigned short* Zb  = bfb + O_ZBF;
  unsigned short* Xb  = bfb + O_XBUF;
  unsigned short* Hz  = bfb + O_HZ;
  unsigned short* Czb = bfb + O_CZB;
  unsigned short* H0n = bfb + O_H0N;
  unsigned short* H1n = bfb + O_H1N;
  unsigned short* H0f = bfb + O_H0F;
  unsigned short* H1f = bfb + O_H1F;
  unsigned short* C0nb = bfb + O_C0NB;
  unsigned short* C1nb = bfb + O_C1NB;
  unsigned short* Rb  = bfb + O_RBUF;
  float* Ghz = f32b + OF_GHZ;
  float* Gcz = f32b + OF_GCZ;
  float* Cz  = f32b + OF_CZ;
  float* C0n = f32b + OF_C0N;
  float* C1n = f32b + OF_C1N;
  float* C0f = f32b + OF_C0F;
  float* C1f = f32b + OF_C1F;

  const int b = (int)blockIdx.x, tid = (int)threadIdx.x;
  const int lane = tid & 63, wave = tid >> 6;
  const int lm = lane & 15, lq8 = (lane >> 4) * 8;
  const int gtid = b * NTHR + tid, gsz = NBLK * NTHR;
  const int c3 = tid & 15;
  const int n03 = 16 * (b & 63);
  unsigned bt = 0;

  // ---- Ph_a: convert weights + z to bf16, init x buffer ----
  conv4(z,     Zb,           (BSZ * LAT) / 4, gtid, gsz);
  conv4(W_ih0, bfb + O_WIH0, 1048576 / 4, gtid, gsz);
  conv4(W_hh0, bfb + O_WHH0, 4194304 / 4, gtid, gsz);
  conv4(W_ih1, bfb + O_WIH1, 4194304 / 4, gtid, gsz);
  conv4(W_hh1, bfb + O_WHH1, 4194304 / 4, gtid, gsz);
  conv4(W_fc1, bfb + O_WFC1, 1048576 / 4, gtid, gsz);
  conv4(W_fc2, bfb + O_WFC2, 262144 / 4, gtid, gsz);
  conv4(Wg_h,  bfb + O_WGH,  2097152 / 4, gtid, gsz);
  conv4(Wg_c,  bfb + O_WGC,  2097152 / 4, gtid, gsz);
  for (int i = gtid; i < BSZ * INP; i += gsz) Xb[i] = f2bf(stok[i & (INP - 1)]);
  gbar_f(bar, ++bt);

  // ---- Ph_b: h_z = tanh(z @ W_lh^T + b_lh); c_z likewise ----
  {
    if (b < 128) {
      f32x4 acc[8] = {};
      const float* Wm = (b < 64) ? W_lh : W_lc;
      mm_f32w<2>(Zb, LAT, Wm, LAT, n03 + lm, wave * 64, lm, lq8, acc);
      dump(lds, acc, wave, lane);
    }
    __syncthreads();
    if (b < 64) {
#pragma unroll
      for (int q = 0; q < 4; ++q) {
        int rq = q * 32 + (tid >> 4);
        float v = ftanh(red8(lds, rq, c3) + b_lh[n03 + c3]);
        unsigned short bv = f2bf(v);
        int i = rq * HID + n03 + c3;
        Hz[i] = bv; H0f[i] = bv; H1f[i] = bv;
      }
    } else if (b < 128) {
#pragma unroll
      for (int q = 0; q < 4; ++q) {
        int rq = q * 32 + (tid >> 4);
        float v = ftanh(red8(lds, rq, c3) + b_lc[n03 + c3]);
        int i = rq * HID + n03 + c3;
        Czb[i] = f2bf(v); Cz[i] = v; C0f[i] = v; C1f[i] = v;
      }
    }
    gbar_f(bar, ++bt);
  }

  // ---- Ph_c: Ghz = h_z @ Wg_h[:,H:2H]^T + bg_h ; Gcz likewise ----
  {
    if (b < 128) {
      f32x4 acc[8] = {};
      const unsigned short* A = (b < 64) ? Hz : Czb;
      const float* Wm = ((b < 64) ? Wg_h : Wg_c) + HID;
      mm_f32w<4>(A, HID, Wm, 2 * HID, n03 + lm, wave * 128, lm, lq8, acc);
      dump(lds, acc, wave, lane);
    }
    __syncthreads();
    if (b < 64) {
#pragma unroll
      for (int q = 0; q < 4; ++q) {
        int rq = q * 32 + (tid >> 4);
        Ghz[rq * HID + n03 + c3] = red8(lds, rq, c3) + bg_h[n03 + c3];
      }
    } else if (b < 128) {
#pragma unroll
      for (int q = 0; q < 4; ++q) {
        int rq = q * 32 + (tid >> 4);
        Gcz[rq * HID + n03 + c3] = red8(lds, rq, c3) + bg_c[n03 + c3];
      }
    }
    gbar_f(bar, ++bt);
  }

  // ---- preload step-invariant scalars into registers ----
  const int du_ = tid & 3, rrow = tid >> 2;
  const int uu = 4 * b + du_;
  const float bi0 = b_ih0[uu] + b_hh0[uu];
  const float bf0 = b_ih0[HID + uu] + b_hh0[HID + uu];
  const float bg0 = b_ih0[2 * HID + uu] + b_hh0[2 * HID + uu];
  const float bo0 = b_ih0[3 * HID + uu] + b_hh0[3 * HID + uu];
  const float bi1 = b_ih1[uu] + b_hh1[uu];
  const float bf1 = b_ih1[HID + uu] + b_hh1[HID + uu];
  const float bg1 = b_ih1[2 * HID + uu] + b_hh1[2 * HID + uu];
  const float bo1 = b_ih1[3 * HID + uu] + b_hh1[3 * HID + uu];

  float p3b = 0.f, p3g[4] = {}, p3z[4] = {};
  if (b < 64) p3b = b_fc1[n03 + c3];
  else if (b < 128) {
#pragma unroll
    for (int q = 0; q < 4; ++q) { int i = (q * 32 + (tid >> 4)) * HID + n03 + c3; p3g[q] = Ghz[i]; p3z[q] = bf2f(Hz[i]); }
  } else if (b < 192) {
#pragma unroll
    for (int q = 0; q < 4; ++q) { int i = (q * 32 + (tid >> 4)) * HID + n03 + c3; p3g[q] = Gcz[i]; p3z[q] = Cz[i]; }
  }
  const int n04 = (b < 16) ? 16 * b : (b < 80) ? 16 * (b - 16) : 16 * (b - 80);
  float p4b = 0.f, p4g[4] = {}, p4z[4] = {};
  if (b < 16) p4b = b_fc2[n04 + c3];
  else if (b < 80) {
#pragma unroll
    for (int q = 0; q < 4; ++q) { int i = (q * 32 + (tid >> 4)) * HID + n04 + c3; p4g[q] = Ghz[i]; p4z[q] = bf2f(Hz[i]); }
  } else if (b < 144) {
#pragma unroll
    for (int q = 0; q < 4; ++q) { int i = (q * 32 + (tid >> 4)) * HID + n04 + c3; p4g[q] = Gcz[i]; p4z[q] = Cz[i]; }
  }

  const int gcol = (lm >> 2) * HID + 4 * b + (lm & 3);   // gate-interleaved column
  const int T = seqp[0];

  for (int t = 0; t < T; ++t) {
    // ---- P1: gates0 = x|W_ih0 + h0f|W_hh0 -> h0n, c0n ----
    {
      f32x4 acc[8] = {};
      mm8(Xb, INP, bfb + O_WIH0, INP, INP,
          H0f, HID, bfb + O_WHH0, HID,
          gcol, wave * 160, wave * 160 + 160, lane, acc);
      dump(lds, acc, wave, lane);
      __syncthreads();
      {
        float s0 = red8(lds, rrow, du_), s1 = red8(lds, rrow, 4 + du_);
        float s2 = red8(lds, rrow, 8 + du_), s3 = red8(lds, rrow, 12 + du_);
        float gi = sigm(s0 + bi0), gf = sigm(s1 + bf0), gg = ftanh(s2 + bg0), go = sigm(s3 + bo0);
        int i = rrow * HID + uu;
        float cn = gf * aldf(C0f + i) + gi * gg;
        unsigned short hb = f2bf(go * ftanh(cn)), cb = f2bf(cn);
        unsigned ho = (unsigned)__shfl_xor((int)(unsigned)hb, 1);
        unsigned co = (unsigned)__shfl_xor((int)(unsigned)cb, 1);
        if ((tid & 1) == 0) {
          ast32(H0n + i, (unsigned)hb | (ho << 16));
          ast32(C0nb + i, (unsigned)cb | (co << 16));
        }
        astf(C0n + i, cn);
      }
      gbar_nf(bar, ++bt);
    }
    // ---- P2: gates1 = h0n|W_ih1 + h1f|W_hh1 -> h1n, c1n ----
    {
      f32x4 acc[8] = {};
      mm8(H0n, HID, bfb + O_WIH1, HID, HID,
          H1f, HID, bfb + O_WHH1, HID,
          gcol, wave * 256, wave * 256 + 256, lane, acc);
      dump(lds, acc, wave, lane);
      __syncthreads();
      {
        float s0 = red8(lds, rrow, du_), s1 = red8(lds, rrow, 4 + du_);
        float s2 = red8(lds, rrow, 8 + du_), s3 = red8(lds, rrow, 12 + du_);
        float gi = sigm(s0 + bi1), gf = sigm(s1 + bf1), gg = ftanh(s2 + bg1), go = sigm(s3 + bo1);
        int i = rrow * HID + uu;
        float cn = gf * aldf(C1f + i) + gi * gg;
        unsigned short hb = f2bf(go * ftanh(cn)), cb = f2bf(cn);
        unsigned ho = (unsigned)__shfl_xor((int)(unsigned)hb, 1);
        unsigned co = (unsigned)__shfl_xor((int)(unsigned)cb, 1);
        if ((tid & 1) == 0) {
          ast32(H1n + i, (unsigned)hb | (ho << 16));
          ast32(C1nb + i, (unsigned)cb | (co << 16));
        }
        astf(C1n + i, cn);
      }
      gbar_nf(bar, ++bt);
    }
    // ---- P3: fc1 | gh0 -> h0f | gc0 -> c0f ----
    {
      if (b < 192) {
        f32x4 acc[8] = {};
        const unsigned short* A = (b < 64) ? H1n : (b < 128) ? H0n : C0nb;
        const unsigned short* Wm; int wp;
        if (b < 64)       { Wm = bfb + O_WFC1; wp = HID; }
        else if (b < 128) { Wm = bfb + O_WGH;  wp = 2 * HID; }
        else              { Wm = bfb + O_WGC;  wp = 2 * HID; }
        mm8(A, HID, Wm, wp, 1 << 30, A, HID, Wm, wp,
            n03 + lm, wave * 128, wave * 128 + 128, lane, acc);
        dump(lds, acc, wave, lane);
      }
      __syncthreads();
      if (b < 64) {
#pragma unroll
        for (int q = 0; q < 4; ++q) {
          int rq = q * 32 + (tid >> 4);
          float v = red8(lds, rq, c3) + p3b;
          unsigned short rv = f2bf(v > 0.f ? v : 0.f);
          unsigned o = (unsigned)__shfl_xor((int)(unsigned)rv, 1);
          if ((tid & 1) == 0) ast32(Rb + rq * HID + n03 + c3, (unsigned)rv | (o << 16));
        }
      } else if (b < 128) {
#pragma unroll
        for (int q = 0; q < 4; ++q) {
          int rq = q * 32 + (tid >> 4); int i = rq * HID + n03 + c3;
          unsigned pw = ald32(H0n + (i & ~1));
          unsigned short mine = (tid & 1) ? (unsigned short)(pw >> 16) : (unsigned short)(pw & 0xffffu);
          float g = sigm(red8(lds, rq, c3) + p3g[q]);
          unsigned short nv = f2bf(g * bf2f(mine) + (1.f - g) * p3z[q]);
          unsigned o = (unsigned)__shfl_xor((int)(unsigned)nv, 1);
          if ((tid & 1) == 0) ast32(H0f + i, (unsigned)nv | (o << 16));
        }
      } else if (b < 192) {
#pragma unroll
        for (int q = 0; q < 4; ++q) {
          int rq = q * 32 + (tid >> 4); int i = rq * HID + n03 + c3;
          float g = sigm(red8(lds, rq, c3) + p3g[q]);
          astf(C0f + i, g * aldf(C0n + i) + (1.f - g) * p3z[q]);
        }
      }
      gbar_nf(bar, ++bt);
    }
    // ---- P4: fc2 -> y_t, x_{t+1} | gh1 -> h1f | gc1 -> c1f ----
    {
      if (b < 144) {
        f32x4 acc[8] = {};
        const unsigned short* A = (b < 16) ? Rb : (b < 80) ? H1n : C1nb;
        const unsigned short* Wm; int wp;
        if (b < 16)      { Wm = bfb + O_WFC2; wp = HID; }
        else if (b < 80) { Wm = bfb + O_WGH;  wp = 2 * HID; }
        else             { Wm = bfb + O_WGC;  wp = 2 * HID; }
        mm8(A, HID, Wm, wp, 1 << 30, A, HID, Wm, wp,
            n04 + lm, wave * 128, wave * 128 + 128, lane, acc);
        dump(lds, acc, wave, lane);
      }
      __syncthreads();
      if (b < 16) {
#pragma unroll
        for (int q = 0; q < 4; ++q) {
          int rq = q * 32 + (tid >> 4);
          float v = red8(lds, rq, c3) + p4b;
          out[((long)rq * T + t) * OUTD + n04 + c3] = v;
          unsigned short xv = f2bf(v);
          unsigned o = (unsigned)__shfl_xor((int)(unsigned)xv, 1);
          if ((tid & 1) == 0) ast32(Xb + rq * INP + n04 + c3, (unsigned)xv | (o << 16));
        }
      } else if (b < 80) {
#pragma unroll
        for (int q = 0; q < 4; ++q) {
          int rq = q * 32 + (tid >> 4); int i = rq * HID + n04 + c3;
          unsigned pw = ald32(H1n + (i & ~1));
          unsigned short mine = (tid & 1) ? (unsigned short)(pw >> 16) : (unsigned short)(pw & 0xffffu);
          float g = sigm(red8(lds, rq, c3) + p4g[q]);
          unsigned short nv = f2bf(g * bf2f(mine) + (1.f - g) * p4z[q]);
          unsigned o = (unsigned)__shfl_xor((int)(unsigned)nv, 1);
          if ((tid & 1) == 0) ast32(H1f + i, (unsigned)nv | (o << 16));
        }
      } else if (b < 144) {
#pragma unroll
        for (int q = 0; q < 4; ++q) {
          int rq = q * 32 + (tid >> 4); int i = rq * HID + n04 + c3;
          float g = sigm(red8(lds, rq, c3) + p4g[q]);
          astf(C1f + i, g * aldf(C1n + i) + (1.f - g) * p4z[q]);
        }
      }
      gbar_nf(bar, ++bt);
    }
  }
}

extern "C" void kernel_launch(void* const* d_in, const int* in_sizes, int n_in,
                              void* d_out, int out_size, void* d_ws, size_t ws_size,
                              hipStream_t stream) {
  unsigned char* ws = (unsigned char*)d_ws;
  hipMemsetAsync(ws + BARBYTE, 0, 2048, stream);

  dec_kernel<<<dim3(NBLK), dim3(NTHR), 0, stream>>>(
      (const float*)d_in[0], (const int*)d_in[1], (const float*)d_in[2],
      (const float*)d_in[3], (const float*)d_in[4], (const float*)d_in[5], (const float*)d_in[6],
      (const float*)d_in[7], (const float*)d_in[8], (const float*)d_in[9], (const float*)d_in[10],
      (const float*)d_in[11], (const float*)d_in[12], (const float*)d_in[13], (const float*)d_in[14],
      (const float*)d_in[15], (const float*)d_in[16], (const float*)d_in[17], (const float*)d_in[18],
      (const float*)d_in[19], (const float*)d_in[20], (const float*)d_in[21], (const float*)d_in[22],
      (float*)d_out, ws);
}